// Round 4
// baseline (11629.724 us; speedup 1.0000x reference)
//
#include <hip/hip_runtime.h>
#include <hip/hip_bf16.h>

#define BB 64
#define TT_ 512
#define IN_ 256
#define HH 1024
#define G4 4096
#define OO 256

typedef _Float16 half8 __attribute__((ext_vector_type(8)));
typedef float f32x4 __attribute__((ext_vector_type(4)));

__device__ __forceinline__ float sigmoidf_(float v) {
    return 1.f / (1.f + __expf(-v));
}
__device__ __forceinline__ float tanhf_(float v) {
    float vc = fminf(fmaxf(v, -15.f), 15.f);
    float e = __expf(2.f * vc);
    return (e - 1.f) / (e + 1.f);
}

// ---------------- weight pack: [Whh | Wih] -> fp16 A-fragment-major ----------------
// Apk[jt(256)][kc(40)][lane(64)][e(8)], jt = j>>4 (j natural 0..4095).
// A-frag (16x16x32): lane l holds A[m = l&15][k = (l>>4)*8 + e].
__global__ __launch_bounds__(256)
void pack_a(const float* __restrict__ Whh, const float* __restrict__ Wih,
            _Float16* __restrict__ Apk)
{
    int id = blockIdx.x * 256 + threadIdx.x;      // < 655360
    int jt = id / 2560;
    int rem = id - jt * 2560;
    int kc = rem >> 6, l = rem & 63;
    int j  = jt * 16 + (l & 15);
    int k0 = (l >> 4) << 3;
    half8 v;
    if (kc < 32) {
        const float* s = Whh + (size_t)j * HH + kc * 32 + k0;
#pragma unroll
        for (int e = 0; e < 8; ++e) v[e] = (_Float16)s[e];
    } else {
        const float* s = Wih + (size_t)j * IN_ + (kc - 32) * 32 + k0;
#pragma unroll
        for (int e = 0; e < 8; ++e) v[e] = (_Float16)s[e];
    }
    ((half8*)Apk)[id] = v;
}

// ---------------- x pack: fp16 B-fragment-major per t ----------------
// Xpk[t][kc2(8)][bt(4)][lane(64)][e(8)]; B-frag: lane l holds B[k=(l>>4)*8+e][n=l&15].
__global__ __launch_bounds__(256)
void pack_x(const float* __restrict__ x, _Float16* __restrict__ Xpk)
{
    int id = blockIdx.x * 256 + threadIdx.x;  // < 1048576
    int l = id & 63, bt = (id >> 6) & 3, kc2 = (id >> 8) & 7, t = id >> 11;
    int b  = bt * 16 + (l & 15);
    int i0 = kc2 * 32 + ((l >> 4) << 3);
    const float* s = x + ((size_t)b * TT_ + t) * IN_ + i0;
    half8 v;
#pragma unroll
    for (int e = 0; e < 8; ++e) v[e] = (_Float16)s[e];
    ((half8*)Xpk)[id] = v;
}

__global__ __launch_bounds__(256)
void pack_bias(const float* __restrict__ bih, const float* __restrict__ bhh,
               float* __restrict__ biasc)
{
    int j = blockIdx.x * 256 + threadIdx.x;
    if (j < G4) biasc[j] = bih[j] + bhh[j];
}

// ---------------- persistent encoder ----------------
// grid 256 = (bq = bid>>6, db = bid&63), block 256 (4 waves). All WGs co-resident
// (capacity >= 1 WG/CU). Wave g holds A[jt = g*64+db] (40 frags = 160 VGPR) in
// registers for all 512 steps; c lives in 1 register/thread. Per step: 40 MFMAs,
// LDS gate exchange, h published via agent-scope 4B atomic stores, flags barrier,
// acquire fence, next step reads h with plain (post-invalidate) loads.
__global__ __launch_bounds__(256, 1)
void enc_persist(const _Float16* __restrict__ Apk,
                 const _Float16* __restrict__ Xpk,
                 _Float16* __restrict__ Hbuf0,
                 _Float16* __restrict__ Hbuf1,
                 const float* __restrict__ biasc,
                 float* __restrict__ cT,
                 float* __restrict__ hT,
                 int* __restrict__ flags)
{
    __shared__ float pre[4][16][16];
    const int tid  = threadIdx.x;
    const int lane = tid & 63, g = tid >> 6;
    const int db = blockIdx.x & 63, bq = blockIdx.x >> 6;
    const int dl = tid >> 4, bl = tid & 15;
    const int myflag = blockIdx.x;

    // ---- one-time: A slice into registers (static indices only) ----
    const half8* A8 = (const half8*)Apk + (size_t)(g * 64 + db) * 40 * 64 + lane;
    half8 areg[40];
#pragma unroll
    for (int kc = 0; kc < 40; ++kc) areg[kc] = A8[kc * 64];

    float bsum[4];
#pragma unroll
    for (int q = 0; q < 4; ++q) bsum[q] = biasc[q * HH + db * 16 + dl];

    float c_reg = 0.f;
    float h_last = 0.f;
    int target = 0;

    for (int t = 0; t < TT_; ++t) {
        const _Float16* Hin = (t & 1) ? Hbuf1 : Hbuf0;
        _Float16* Hout      = (t & 1) ? Hbuf0 : Hbuf1;
        const half8* H8 = (const half8*)Hin + lane;
        const half8* X8 = (const half8*)Xpk + (size_t)t * 32 * 64 + lane;

        f32x4 acc0 = {0.f, 0.f, 0.f, 0.f};
        f32x4 acc1 = {0.f, 0.f, 0.f, 0.f};
#pragma unroll
        for (int kc = 0; kc < 32; ++kc) {
            half8 bf = H8[(kc * 4 + bq) * 64];
            if (kc & 1)
                acc1 = __builtin_amdgcn_mfma_f32_16x16x32_f16(areg[kc], bf, acc1, 0, 0, 0);
            else
                acc0 = __builtin_amdgcn_mfma_f32_16x16x32_f16(areg[kc], bf, acc0, 0, 0, 0);
        }
#pragma unroll
        for (int kc2 = 0; kc2 < 8; ++kc2) {
            half8 bf = X8[(kc2 * 4 + bq) * 64];
            if (kc2 & 1)
                acc1 = __builtin_amdgcn_mfma_f32_16x16x32_f16(areg[32 + kc2], bf, acc1, 0, 0, 0);
            else
                acc0 = __builtin_amdgcn_mfma_f32_16x16x32_f16(areg[32 + kc2], bf, acc0, 0, 0, 0);
        }

        // D layout: row = (lane>>4)*4 + r, col = lane&15
#pragma unroll
        for (int r = 0; r < 4; ++r)
            pre[g][(lane >> 4) * 4 + r][lane & 15] = acc0[r] + acc1[r];
        __syncthreads();

        // ---- gates: thread = (dl, bl) ----
        float pi = pre[0][dl][bl] + bsum[0];
        float pf = pre[1][dl][bl] + bsum[1];
        float pg = pre[2][dl][bl] + bsum[2];
        float po = pre[3][dl][bl] + bsum[3];
        float ig = sigmoidf_(pi), fg = sigmoidf_(pf);
        float gg = tanhf_(pg),    og = sigmoidf_(po);
        c_reg = fg * c_reg + ig * gg;
        float h = og * tanhf_(c_reg);
        h_last = h;

        // ---- publish h (pack d-pairs via shfl, 4B agent-scope stores) ----
        float hp = __shfl_xor(h, 16);     // partner dl^1
        if (!(dl & 1)) {
            _Float16 h0 = (_Float16)h, h1 = (_Float16)hp;
            unsigned int pk = (unsigned int)__builtin_bit_cast(unsigned short, h0) |
                              ((unsigned int)__builtin_bit_cast(unsigned short, h1) << 16);
            int d = db * 16 + dl;          // even
            size_t idx = ((((size_t)(d >> 5) * 4 + bq) * 64) +
                          ((d >> 3) & 3) * 16 + bl) * 8 + (d & 7);
            __hip_atomic_store((unsigned int*)&Hout[idx], pk,
                               __ATOMIC_RELAXED, __HIP_MEMORY_SCOPE_AGENT);
        }
        __syncthreads();   // drains all waves' stores (vmcnt 0 before barrier)

        // ---- barrier: arrive + spin ----
        ++target;
        if (tid == 0)
            __hip_atomic_store(&flags[myflag], target,
                               __ATOMIC_RELEASE, __HIP_MEMORY_SCOPE_AGENT);
        if (t < TT_ - 1) {
            int ok;
            int first = 1;
            do {
                if (!first) __builtin_amdgcn_s_sleep(1);
                first = 0;
                int v = __hip_atomic_load(&flags[tid],
                                          __ATOMIC_RELAXED, __HIP_MEMORY_SCOPE_AGENT);
                ok = (v >= target);
            } while (__syncthreads_and(ok) == 0);
            __builtin_amdgcn_fence(__ATOMIC_ACQUIRE, "agent");
        }
    }

    // ---- final state for decoder ----
    int d = db * 16 + dl, bg = bq * 16 + bl;
    cT[d * 64 + bg] = c_reg;
    hT[d * 64 + bg] = h_last;
}

// ---------------- hdec = h_final @ dec_Whh^T + dec_bih + dec_bhh ----------------
__global__ __launch_bounds__(256)
void hdec_kernel(const float* __restrict__ hT, const float* __restrict__ Whh,
                 const float* __restrict__ bih, const float* __restrict__ bhh,
                 float* __restrict__ hdec)
{
    __shared__ float hb[1024];
    const int tid = threadIdx.x;
    const int b  = blockIdx.x >> 2;
    const int j0 = (blockIdx.x & 3) * 1024;
#pragma unroll
    for (int u = 0; u < 4; ++u) {
        int k = u * 256 + tid;
        hb[k] = hT[k * 64 + b];
    }
    __syncthreads();
#pragma unroll
    for (int rr = 0; rr < 4; ++rr) {
        int j = j0 + rr * 256 + tid;
        const float* wr = Whh + (size_t)j * HH;
        float a = bih[j] + bhh[j];
        for (int k = 0; k < 1024; k += 4) {
            float4 wv = *(const float4*)(wr + k);
            float4 hv = *(const float4*)&hb[k];
            a += hv.x * wv.x + hv.y * wv.y + hv.z * wv.z + hv.w * wv.w;
        }
        hdec[(size_t)b * G4 + j] = a;
    }
}

// ---------------- fused decoder: pre -> gates -> h_new -> FC ----------------
__global__ __launch_bounds__(256)
void dec_fused(const float* __restrict__ x, const float* __restrict__ Wih,
               const float* __restrict__ hdec, const float* __restrict__ cT,
               const float* __restrict__ fcW, const float* __restrict__ fcb,
               float* __restrict__ out)
{
    __shared__ __align__(16) float xs[16][256];              // 16 KB
    __shared__ __align__(16) __hip_bfloat16 ps[4][16][512];  // 64 KB
    const int tid = threadIdx.x;
    const int w  = blockIdx.x;
    const int b  = w >> 5;
    const int t0 = (w & 31) * 16;

#pragma unroll
    for (int u = 0; u < 16; ++u) {
        int e = u * 256 + tid;
        int tt = e >> 8, k = e & 255;
        xs[tt][k] = x[(size_t)b * (TT_ * IN_) + (size_t)(t0 + tt) * IN_ + k];
    }

    float facc[16];
#pragma unroll
    for (int tt = 0; tt < 16; ++tt) facc[tt] = fcb[tid];

    for (int dc = 0; dc < 2; ++dc) {
        __syncthreads();
        for (int q = 0; q < 4; ++q) {
            int ja = q * HH + dc * 512 + tid;
            int jb = ja + 256;
            float ha = hdec[(size_t)b * G4 + ja];
            float hb2 = hdec[(size_t)b * G4 + jb];
            float aa[16], ab[16];
#pragma unroll
            for (int tt = 0; tt < 16; ++tt) { aa[tt] = ha; ab[tt] = hb2; }
            const float* wa = Wih + (size_t)ja * IN_;
            const float* wb = Wih + (size_t)jb * IN_;
            for (int k = 0; k < 256; k += 4) {
                float4 va = *(const float4*)(wa + k);
                float4 vb = *(const float4*)(wb + k);
#pragma unroll
                for (int tt = 0; tt < 16; ++tt) {
                    float4 xv = *(const float4*)&xs[tt][k];
                    aa[tt] += xv.x * va.x + xv.y * va.y + xv.z * va.z + xv.w * va.w;
                    ab[tt] += xv.x * vb.x + xv.y * vb.y + xv.z * vb.z + xv.w * vb.w;
                }
            }
#pragma unroll
            for (int tt = 0; tt < 16; ++tt) {
                ps[q][tt][tid]       = __float2bfloat16(aa[tt]);
                ps[q][tt][tid + 256] = __float2bfloat16(ab[tt]);
            }
        }
        __syncthreads();

        float hn[32];
#pragma unroll
        for (int vv = 0; vv < 32; ++vv) {
            int p = vv * 256 + tid;
            int dl = p & 511, tt = p >> 9;
            float ig = __bfloat162float(ps[0][tt][dl]);
            float fg = __bfloat162float(ps[1][tt][dl]);
            float gg = __bfloat162float(ps[2][tt][dl]);
            float og = __bfloat162float(ps[3][tt][dl]);
            ig = sigmoidf_(ig); fg = sigmoidf_(fg);
            gg = tanhf_(gg);    og = sigmoidf_(og);
            float cv = cT[(dc * 512 + dl) * 64 + b];
            float cn = fg * cv + ig * gg;
            hn[vv] = og * tanhf_(cn);
        }
        __syncthreads();
        float* hnf = (float*)&ps[0][0][0];
#pragma unroll
        for (int vv = 0; vv < 32; ++vv) {
            int p = vv * 256 + tid;
            int dl = p & 511, tt = p >> 9;
            hnf[tt * 512 + dl] = hn[vv];
        }
        __syncthreads();

        const float* wo = fcW + (size_t)tid * HH + dc * 512;
        for (int k = 0; k < 512; k += 4) {
            float4 wv = *(const float4*)(wo + k);
#pragma unroll
            for (int tt = 0; tt < 16; ++tt) {
                float4 hv = *(const float4*)&hnf[tt * 512 + k];
                facc[tt] += hv.x * wv.x + hv.y * wv.y + hv.z * wv.z + hv.w * wv.w;
            }
        }
    }

#pragma unroll
    for (int tt = 0; tt < 16; ++tt) {
        out[(size_t)b * (TT_ * OO) + (size_t)(t0 + tt) * OO + tid] = facc[tt];
    }
}

extern "C" void kernel_launch(void* const* d_in, const int* in_sizes, int n_in,
                              void* d_out, int out_size, void* d_ws, size_t ws_size,
                              hipStream_t stream) {
    const float* x    = (const float*)d_in[0];
    const float* eWih = (const float*)d_in[1];
    const float* eWhh = (const float*)d_in[2];
    const float* ebih = (const float*)d_in[3];
    const float* ebhh = (const float*)d_in[4];
    const float* dWih = (const float*)d_in[5];
    const float* dWhh = (const float*)d_in[6];
    const float* dbih = (const float*)d_in[7];
    const float* dbhh = (const float*)d_in[8];
    const float* fcW  = (const float*)d_in[9];
    const float* fcb  = (const float*)d_in[10];

    // ws layout (f32 words): hT 65536 | cT 65536 | hdec 262144 | biasc 4096 |
    // flags 256 | pad | fp16: Hf0 65536 | Hf1 65536 | Apk 5242880 | Xpk 8388608
    float* ws    = (float*)d_ws;
    float* hT    = ws;
    float* cT    = ws + 65536;
    float* hdec  = ws + 131072;
    float* biasc = ws + 393216;
    int*   flags = (int*)(ws + 397312);
    _Float16* fp  = (_Float16*)(ws + 397568);
    _Float16* Hf0 = fp;
    _Float16* Hf1 = fp + 65536;
    _Float16* Apk = fp + 131072;
    _Float16* Xpk = Apk + 5242880;

    pack_a<<<dim3(2560), dim3(256), 0, stream>>>(eWhh, eWih, Apk);
    pack_x<<<dim3(4096), dim3(256), 0, stream>>>(x, Xpk);
    pack_bias<<<dim3(16), dim3(256), 0, stream>>>(ebih, ebhh, biasc);
    hipMemsetAsync(flags, 0, 256 * sizeof(int), stream);
    hipMemsetAsync(Hf0, 0, 65536 * sizeof(_Float16), stream);

    enc_persist<<<dim3(256), dim3(256), 0, stream>>>(
        Apk, Xpk, Hf0, Hf1, biasc, cT, hT, flags);

    hdec_kernel<<<dim3(256), dim3(256), 0, stream>>>(hT, dWhh, dbih, dbhh, hdec);
    dec_fused<<<dim3(2048), dim3(256), 0, stream>>>(x, dWih, hdec, cT, fcW, fcb,
                                                    (float*)d_out);
}

// Round 5
// 9428.017 us; speedup vs baseline: 1.2335x; 1.2335x over previous
//
#include <hip/hip_runtime.h>
#include <hip/hip_bf16.h>

#define BB 64
#define TT_ 512
#define IN_ 256
#define HH 1024
#define G4 4096
#define OO 256

typedef _Float16 half8 __attribute__((ext_vector_type(8)));
typedef float f32x4 __attribute__((ext_vector_type(4)));

__device__ __forceinline__ float sigmoidf_(float v) {
    return 1.f / (1.f + __expf(-v));
}
__device__ __forceinline__ float tanhf_(float v) {
    float vc = fminf(fmaxf(v, -15.f), 15.f);
    float e = __expf(2.f * vc);
    return (e - 1.f) / (e + 1.f);
}

// ---------------- weight pack v2 ----------------
// Apk[dq(128)][t2(2)][kc(40)][lane(64)][e(8)] fp16.
// A-tile rows: rD = ddl*4 + g  (ddl = local dim 0..3, g = gate), so MFMA acc[r]
// of lane q=l>>4 holds gate r of dim dq*8 + t2*4 + q  -> gates fused in-register.
// A-frag: lane l holds A[m = l&15][k = (l>>4)*8 + e].
__global__ __launch_bounds__(256)
void pack_a2(const float* __restrict__ Whh, const float* __restrict__ Wih,
             _Float16* __restrict__ Apk)
{
    int id = blockIdx.x * 256 + threadIdx.x;      // 16B-unit id < 655360
    int dq  = id / 5120;
    int r1  = id - dq * 5120;
    int t2  = r1 / 2560;
    int r2  = r1 - t2 * 2560;
    int kc  = r2 >> 6, l = r2 & 63;
    int rD  = l & 15;
    int g   = rD & 3, ddl = rD >> 2;
    int d   = dq * 8 + t2 * 4 + ddl;
    int j   = g * HH + d;
    int k0  = kc * 32 + ((l >> 4) << 3);
    half8 v;
    if (kc < 32) {
        const float* s = Whh + (size_t)j * HH + k0;
#pragma unroll
        for (int e = 0; e < 8; ++e) v[e] = (_Float16)s[e];
    } else {
        const float* s = Wih + (size_t)j * IN_ + (k0 - 1024);
#pragma unroll
        for (int e = 0; e < 8; ++e) v[e] = (_Float16)s[e];
    }
    ((half8*)Apk)[id] = v;
}

// ---------------- x pack: fp16 B-fragment-major per t ----------------
// Xpk[t][kc2(8)][bq4(4)][lane(64)][e(8)]; B-frag: lane l holds B[k=(l>>4)*8+e][n=l&15].
__global__ __launch_bounds__(256)
void pack_x(const float* __restrict__ x, _Float16* __restrict__ Xpk)
{
    int id = blockIdx.x * 256 + threadIdx.x;  // < 1048576
    int l = id & 63, bt = (id >> 6) & 3, kc2 = (id >> 8) & 7, t = id >> 11;
    int b  = bt * 16 + (l & 15);
    int i0 = kc2 * 32 + ((l >> 4) << 3);
    const float* s = x + ((size_t)b * TT_ + t) * IN_ + i0;
    half8 v;
#pragma unroll
    for (int e = 0; e < 8; ++e) v[e] = (_Float16)s[e];
    ((half8*)Xpk)[id] = v;
}

__global__ __launch_bounds__(256)
void pack_bias(const float* __restrict__ bih, const float* __restrict__ bhh,
               float* __restrict__ biasc)
{
    int j = blockIdx.x * 256 + threadIdx.x;
    if (j < G4) biasc[j] = bih[j] + bhh[j];
}

// ---------------- persistent encoder v2 ----------------
// grid 256 = (dq = bid>>1, bh = bid&1), block 256 (4 waves: t2 = w>>1, bql = w&1).
// A (80KB) in LDS once; H (64KB/WG slice) staged into LDS per step via agent-scope
// atomic loads (cross-XCD coherent, no L2-nuking fence). Gates fused in-register.
// Barrier: per-WG flag release-store + wave0-only poll.
__global__ __launch_bounds__(256, 1)
void enc_persist(const _Float16* __restrict__ Apk,
                 const _Float16* __restrict__ Xpk,
                 _Float16* __restrict__ Hbuf0,
                 _Float16* __restrict__ Hbuf1,
                 const float* __restrict__ biasc,
                 float* __restrict__ cT,
                 float* __restrict__ hT,
                 int* __restrict__ flags)
{
    __shared__ _Float16 Alds[2 * 40 * 64 * 8];   // 80 KB
    __shared__ _Float16 Hlds[2 * 32 * 64 * 8];   // 64 KB
    const int tid  = threadIdx.x;
    const int lane = tid & 63, w = tid >> 6;
    const int t2 = w >> 1, bql = w & 1;
    const int dq = blockIdx.x >> 1, bh = blockIdx.x & 1;
    const int q  = lane >> 4, bl = lane & 15;
    const int d  = dq * 8 + t2 * 4 + q;          // this thread's dim
    const int b  = bh * 32 + bql * 16 + bl;      // this thread's batch
    const int bq4 = bh * 2 + bql;                // global 16-batch slice

    // ---- one-time: A slice -> LDS (coalesced 16B) ----
    const half8* Asrc = (const half8*)Apk + (size_t)dq * 5120;
    half8* Ald8 = (half8*)Alds;
#pragma unroll
    for (int i = 0; i < 20; ++i)
        Ald8[i * 256 + tid] = Asrc[i * 256 + tid];

    float bsum[4];
#pragma unroll
    for (int g2 = 0; g2 < 4; ++g2) bsum[g2] = biasc[g2 * HH + d];

    const half8* Hld8 = (const half8*)Hlds;
    unsigned long long* Hld64 = (unsigned long long*)Hlds;

    float c_reg = 0.f, h_last = 0.f;
    int target = 0;
    __syncthreads();   // A-LDS ready

    for (int t = 0; t < TT_; ++t) {
        const _Float16* Hin = (t & 1) ? Hbuf1 : Hbuf0;
        _Float16* Hout      = (t & 1) ? Hbuf0 : Hbuf1;

        // ---- stage this WG's two 16-batch H slices into LDS (coherent loads) ----
        const unsigned long long* Hsrc = (const unsigned long long*)Hin;
#pragma unroll
        for (int i = 0; i < 16; ++i) {
            int seq = i * 256 + tid;                  // 16B units, 4096 total
            int bqs = seq >> 11, kc = (seq >> 6) & 31, l2 = seq & 63;
            int off = (kc * 4 + bh * 2 + bqs) * 64 + l2;
            unsigned long long a0 = __hip_atomic_load(Hsrc + (size_t)off * 2,
                                       __ATOMIC_RELAXED, __HIP_MEMORY_SCOPE_AGENT);
            unsigned long long a1 = __hip_atomic_load(Hsrc + (size_t)off * 2 + 1,
                                       __ATOMIC_RELAXED, __HIP_MEMORY_SCOPE_AGENT);
            Hld64[seq * 2]     = a0;
            Hld64[seq * 2 + 1] = a1;
        }
        __syncthreads();   // H-LDS ready

        // ---- MFMA: D[16 rows = 4dim x 4gate][16 batches], K = 1280 ----
        const half8* X8 = (const half8*)Xpk + ((size_t)t * 8 * 4 + bq4) * 64 + lane;
        f32x4 acc = {0.f, 0.f, 0.f, 0.f};
#pragma unroll
        for (int kc2 = 0; kc2 < 8; ++kc2) {
            half8 a  = Ald8[(t2 * 40 + 32 + kc2) * 64 + lane];
            half8 bf = X8[kc2 * 256];
            acc = __builtin_amdgcn_mfma_f32_16x16x32_f16(a, bf, acc, 0, 0, 0);
        }
#pragma unroll
        for (int kc = 0; kc < 32; ++kc) {
            half8 a  = Ald8[(t2 * 40 + kc) * 64 + lane];
            half8 bf = Hld8[(bql * 32 + kc) * 64 + lane];
            acc = __builtin_amdgcn_mfma_f32_16x16x32_f16(a, bf, acc, 0, 0, 0);
        }

        // ---- gates fully in-register: acc[r] = gate r of dim d ----
        float pi = acc[0] + bsum[0];
        float pf = acc[1] + bsum[1];
        float pg = acc[2] + bsum[2];
        float po = acc[3] + bsum[3];
        float ig = sigmoidf_(pi), fg = sigmoidf_(pf);
        float gg = tanhf_(pg),    og = sigmoidf_(po);
        c_reg = fg * c_reg + ig * gg;
        float h = og * tanhf_(c_reg);
        h_last = h;

        // ---- publish h in B-frag layout (pack d-pairs via shfl, 4B stores) ----
        float hp = __shfl_xor(h, 16);   // partner q^1 -> dim d^1
        if (!(q & 1)) {
            _Float16 h0 = (_Float16)h, h1 = (_Float16)hp;
            unsigned int pk = (unsigned int)__builtin_bit_cast(unsigned short, h0) |
                              ((unsigned int)__builtin_bit_cast(unsigned short, h1) << 16);
            size_t idx = ((size_t)(d >> 5) * 4 + (b >> 4)) * 512 +
                         ((d >> 3) & 3) * 128 + bl * 8 + (d & 7);
            __hip_atomic_store((unsigned int*)&Hout[idx], pk,
                               __ATOMIC_RELAXED, __HIP_MEMORY_SCOPE_AGENT);
        }
        __syncthreads();   // drain all waves' stores (vmcnt 0 before barrier)

        // ---- arrive + wave0 poll ----
        ++target;
        if (tid == 0)
            __hip_atomic_store(&flags[blockIdx.x], target,
                               __ATOMIC_RELEASE, __HIP_MEMORY_SCOPE_AGENT);
        if (t < TT_ - 1) {
            if (w == 0) {
                int base = lane * 4;
                for (;;) {
                    int m0 = __hip_atomic_load(&flags[base],
                                 __ATOMIC_RELAXED, __HIP_MEMORY_SCOPE_AGENT);
                    int m1 = __hip_atomic_load(&flags[base + 1],
                                 __ATOMIC_RELAXED, __HIP_MEMORY_SCOPE_AGENT);
                    int m2 = __hip_atomic_load(&flags[base + 2],
                                 __ATOMIC_RELAXED, __HIP_MEMORY_SCOPE_AGENT);
                    int m3 = __hip_atomic_load(&flags[base + 3],
                                 __ATOMIC_RELAXED, __HIP_MEMORY_SCOPE_AGENT);
                    int mn = min(min(m0, m1), min(m2, m3));
                    if (__all(mn >= target)) break;
                    __builtin_amdgcn_s_sleep(2);
                }
            }
            __syncthreads();   // release all waves; also orders next H-stage
        }
    }

    // ---- final state for decoder ----
    cT[d * 64 + b] = c_reg;
    hT[d * 64 + b] = h_last;
}

// ---------------- hdec = h_final @ dec_Whh^T + dec_bih + dec_bhh ----------------
__global__ __launch_bounds__(256)
void hdec_kernel(const float* __restrict__ hT, const float* __restrict__ Whh,
                 const float* __restrict__ bih, const float* __restrict__ bhh,
                 float* __restrict__ hdec)
{
    __shared__ float hb[1024];
    const int tid = threadIdx.x;
    const int b  = blockIdx.x >> 2;
    const int j0 = (blockIdx.x & 3) * 1024;
#pragma unroll
    for (int u = 0; u < 4; ++u) {
        int k = u * 256 + tid;
        hb[k] = hT[k * 64 + b];
    }
    __syncthreads();
#pragma unroll
    for (int rr = 0; rr < 4; ++rr) {
        int j = j0 + rr * 256 + tid;
        const float* wr = Whh + (size_t)j * HH;
        float a = bih[j] + bhh[j];
        for (int k = 0; k < 1024; k += 4) {
            float4 wv = *(const float4*)(wr + k);
            float4 hv = *(const float4*)&hb[k];
            a += hv.x * wv.x + hv.y * wv.y + hv.z * wv.z + hv.w * wv.w;
        }
        hdec[(size_t)b * G4 + j] = a;
    }
}

// ---------------- fused decoder: pre -> gates -> h_new -> FC ----------------
__global__ __launch_bounds__(256)
void dec_fused(const float* __restrict__ x, const float* __restrict__ Wih,
               const float* __restrict__ hdec, const float* __restrict__ cT,
               const float* __restrict__ fcW, const float* __restrict__ fcb,
               float* __restrict__ out)
{
    __shared__ __align__(16) float xs[16][256];              // 16 KB
    __shared__ __align__(16) __hip_bfloat16 ps[4][16][512];  // 64 KB
    const int tid = threadIdx.x;
    const int w  = blockIdx.x;
    const int b  = w >> 5;
    const int t0 = (w & 31) * 16;

#pragma unroll
    for (int u = 0; u < 16; ++u) {
        int e = u * 256 + tid;
        int tt = e >> 8, k = e & 255;
        xs[tt][k] = x[(size_t)b * (TT_ * IN_) + (size_t)(t0 + tt) * IN_ + k];
    }

    float facc[16];
#pragma unroll
    for (int tt = 0; tt < 16; ++tt) facc[tt] = fcb[tid];

    for (int dc = 0; dc < 2; ++dc) {
        __syncthreads();
        for (int q = 0; q < 4; ++q) {
            int ja = q * HH + dc * 512 + tid;
            int jb = ja + 256;
            float ha = hdec[(size_t)b * G4 + ja];
            float hb2 = hdec[(size_t)b * G4 + jb];
            float aa[16], ab[16];
#pragma unroll
            for (int tt = 0; tt < 16; ++tt) { aa[tt] = ha; ab[tt] = hb2; }
            const float* wa = Wih + (size_t)ja * IN_;
            const float* wb = Wih + (size_t)jb * IN_;
            for (int k = 0; k < 256; k += 4) {
                float4 va = *(const float4*)(wa + k);
                float4 vb = *(const float4*)(wb + k);
#pragma unroll
                for (int tt = 0; tt < 16; ++tt) {
                    float4 xv = *(const float4*)&xs[tt][k];
                    aa[tt] += xv.x * va.x + xv.y * va.y + xv.z * va.z + xv.w * va.w;
                    ab[tt] += xv.x * vb.x + xv.y * vb.y + xv.z * vb.z + xv.w * vb.w;
                }
            }
#pragma unroll
            for (int tt = 0; tt < 16; ++tt) {
                ps[q][tt][tid]       = __float2bfloat16(aa[tt]);
                ps[q][tt][tid + 256] = __float2bfloat16(ab[tt]);
            }
        }
        __syncthreads();

        float hn[32];
#pragma unroll
        for (int vv = 0; vv < 32; ++vv) {
            int p = vv * 256 + tid;
            int dl = p & 511, tt = p >> 9;
            float ig = __bfloat162float(ps[0][tt][dl]);
            float fg = __bfloat162float(ps[1][tt][dl]);
            float gg = __bfloat162float(ps[2][tt][dl]);
            float og = __bfloat162float(ps[3][tt][dl]);
            ig = sigmoidf_(ig); fg = sigmoidf_(fg);
            gg = tanhf_(gg);    og = sigmoidf_(og);
            float cv = cT[(dc * 512 + dl) * 64 + b];
            float cn = fg * cv + ig * gg;
            hn[vv] = og * tanhf_(cn);
        }
        __syncthreads();
        float* hnf = (float*)&ps[0][0][0];
#pragma unroll
        for (int vv = 0; vv < 32; ++vv) {
            int p = vv * 256 + tid;
            int dl = p & 511, tt = p >> 9;
            hnf[tt * 512 + dl] = hn[vv];
        }
        __syncthreads();

        const float* wo = fcW + (size_t)tid * HH + dc * 512;
        for (int k = 0; k < 512; k += 4) {
            float4 wv = *(const float4*)(wo + k);
#pragma unroll
            for (int tt = 0; tt < 16; ++tt) {
                float4 hv = *(const float4*)&hnf[tt * 512 + k];
                facc[tt] += hv.x * wv.x + hv.y * wv.y + hv.z * wv.z + hv.w * wv.w;
            }
        }
    }

#pragma unroll
    for (int tt = 0; tt < 16; ++tt) {
        out[(size_t)b * (TT_ * OO) + (size_t)(t0 + tt) * OO + tid] = facc[tt];
    }
}

extern "C" void kernel_launch(void* const* d_in, const int* in_sizes, int n_in,
                              void* d_out, int out_size, void* d_ws, size_t ws_size,
                              hipStream_t stream) {
    const float* x    = (const float*)d_in[0];
    const float* eWih = (const float*)d_in[1];
    const float* eWhh = (const float*)d_in[2];
    const float* ebih = (const float*)d_in[3];
    const float* ebhh = (const float*)d_in[4];
    const float* dWih = (const float*)d_in[5];
    const float* dWhh = (const float*)d_in[6];
    const float* dbih = (const float*)d_in[7];
    const float* dbhh = (const float*)d_in[8];
    const float* fcW  = (const float*)d_in[9];
    const float* fcb  = (const float*)d_in[10];

    // ws layout (f32 words): hT 65536 | cT 65536 | hdec 262144 | biasc 4096 |
    // flags 256 | fp16: Hf0 65536 | Hf1 65536 | Apk 5242880 | Xpk 8388608
    float* ws    = (float*)d_ws;
    float* hT    = ws;
    float* cT    = ws + 65536;
    float* hdec  = ws + 131072;
    float* biasc = ws + 393216;
    int*   flags = (int*)(ws + 397312);
    _Float16* fp  = (_Float16*)(ws + 397568);
    _Float16* Hf0 = fp;
    _Float16* Hf1 = fp + 65536;
    _Float16* Apk = fp + 131072;
    _Float16* Xpk = Apk + 5242880;

    pack_a2<<<dim3(2560), dim3(256), 0, stream>>>(eWhh, eWih, Apk);
    pack_x<<<dim3(4096), dim3(256), 0, stream>>>(x, Xpk);
    pack_bias<<<dim3(16), dim3(256), 0, stream>>>(ebih, ebhh, biasc);
    hipMemsetAsync(flags, 0, 256 * sizeof(int), stream);
    hipMemsetAsync(Hf0, 0, 65536 * sizeof(_Float16), stream);

    enc_persist<<<dim3(256), dim3(256), 0, stream>>>(
        Apk, Xpk, Hf0, Hf1, biasc, cT, hT, flags);

    hdec_kernel<<<dim3(256), dim3(256), 0, stream>>>(hT, dWhh, dbih, dbhh, hdec);
    dec_fused<<<dim3(2048), dim3(256), 0, stream>>>(x, dWih, hdec, cT, fcW, fcb,
                                                    (float*)d_out);
}

// Round 6
// 6618.217 us; speedup vs baseline: 1.7572x; 1.4246x over previous
//
#include <hip/hip_runtime.h>
#include <hip/hip_bf16.h>

#define BB 64
#define TT_ 512
#define IN_ 256
#define HH 1024
#define G4 4096
#define OO 256

typedef _Float16 half8 __attribute__((ext_vector_type(8)));
typedef float f32x4 __attribute__((ext_vector_type(4)));
typedef unsigned int uint4v __attribute__((ext_vector_type(4)));
typedef int int4v __attribute__((ext_vector_type(4)));

__device__ __forceinline__ float sigmoidf_(float v) {
    return 1.f / (1.f + __expf(-v));
}
__device__ __forceinline__ float tanhf_(float v) {
    float vc = fminf(fmaxf(v, -15.f), 15.f);
    float e = __expf(2.f * vc);
    return (e - 1.f) / (e + 1.f);
}

// ---------------- weight pack v2 ----------------
// Apk[dq(128)][t2(2)][kc(40)][lane(64)][e(8)] fp16.
// A-tile rows: rD = ddl*4 + g, so MFMA acc[r] of lane q=l>>4 holds gate r of
// dim dq*8 + t2*4 + q -> gates fused in-register.
__global__ __launch_bounds__(256)
void pack_a2(const float* __restrict__ Whh, const float* __restrict__ Wih,
             _Float16* __restrict__ Apk)
{
    int id = blockIdx.x * 256 + threadIdx.x;      // 16B-unit id < 655360
    int dq  = id / 5120;
    int r1  = id - dq * 5120;
    int t2  = r1 / 2560;
    int r2  = r1 - t2 * 2560;
    int kc  = r2 >> 6, l = r2 & 63;
    int rD  = l & 15;
    int g   = rD & 3, ddl = rD >> 2;
    int d   = dq * 8 + t2 * 4 + ddl;
    int j   = g * HH + d;
    int k0  = kc * 32 + ((l >> 4) << 3);
    half8 v;
    if (kc < 32) {
        const float* s = Whh + (size_t)j * HH + k0;
#pragma unroll
        for (int e = 0; e < 8; ++e) v[e] = (_Float16)s[e];
    } else {
        const float* s = Wih + (size_t)j * IN_ + (k0 - 1024);
#pragma unroll
        for (int e = 0; e < 8; ++e) v[e] = (_Float16)s[e];
    }
    ((half8*)Apk)[id] = v;
}

// ---------------- x pack: fp16 B-fragment-major per t ----------------
__global__ __launch_bounds__(256)
void pack_x(const float* __restrict__ x, _Float16* __restrict__ Xpk)
{
    int id = blockIdx.x * 256 + threadIdx.x;  // < 1048576
    int l = id & 63, bt = (id >> 6) & 3, kc2 = (id >> 8) & 7, t = id >> 11;
    int b  = bt * 16 + (l & 15);
    int i0 = kc2 * 32 + ((l >> 4) << 3);
    const float* s = x + ((size_t)b * TT_ + t) * IN_ + i0;
    half8 v;
#pragma unroll
    for (int e = 0; e < 8; ++e) v[e] = (_Float16)s[e];
    ((half8*)Xpk)[id] = v;
}

__global__ __launch_bounds__(256)
void pack_bias(const float* __restrict__ bih, const float* __restrict__ bhh,
               float* __restrict__ biasc)
{
    int j = blockIdx.x * 256 + threadIdx.x;
    if (j < G4) biasc[j] = bih[j] + bhh[j];
}

// ---------------- persistent encoder v3 ----------------
// grid 256 = (dq = bid>>1, bh = bid&1), block 256 (4 waves: t2 = w>>1, bql = w&1).
// A (80KB) in LDS once. Per step: H staged via 16 pipelined sc0sc1 dwordx4 loads
// (one LLC round trip), MFMA 2-chain, gates in-register, publish via sc0sc1
// 4B stores, flag barrier with pipelined dwordx4 poll. No HW fences in the loop.
__global__ __launch_bounds__(256, 1)
void enc_persist(const _Float16* __restrict__ Apk,
                 const _Float16* __restrict__ Xpk,
                 _Float16* __restrict__ Hbuf0,
                 _Float16* __restrict__ Hbuf1,
                 const float* __restrict__ biasc,
                 float* __restrict__ cT,
                 float* __restrict__ hT,
                 int* __restrict__ flags)
{
    __shared__ __align__(16) _Float16 Alds[2 * 40 * 64 * 8];   // 80 KB
    __shared__ __align__(16) _Float16 Hlds[2 * 32 * 64 * 8];   // 64 KB
    const int tid  = threadIdx.x;
    const int lane = tid & 63, w = tid >> 6;
    const int t2 = w >> 1, bql = w & 1;
    const int dq = blockIdx.x >> 1, bh = blockIdx.x & 1;
    const int q  = lane >> 4, bl = lane & 15;
    const int d  = dq * 8 + t2 * 4 + q;          // this thread's dim
    const int b  = bh * 32 + bql * 16 + bl;      // this thread's batch
    const int bq4 = bh * 2 + bql;                // global 16-batch slice

    // ---- one-time: A slice -> LDS (coalesced 16B) ----
    const half8* Asrc = (const half8*)Apk + (size_t)dq * 5120;
    half8* Ald8 = (half8*)Alds;
#pragma unroll
    for (int i = 0; i < 20; ++i)
        Ald8[i * 256 + tid] = Asrc[i * 256 + tid];

    float bsum[4];
#pragma unroll
    for (int g2 = 0; g2 < 4; ++g2) bsum[g2] = biasc[g2 * HH + d];

    const half8* Hld8 = (const half8*)Hlds;
    uint4v* Hld16 = (uint4v*)Hlds;

    float c_reg = 0.f, h_last = 0.f;
    __syncthreads();   // A-LDS ready

    for (int t = 0; t < TT_; ++t) {
        const _Float16* Hin = (t & 1) ? Hbuf1 : Hbuf0;
        _Float16* Hout      = (t & 1) ? Hbuf0 : Hbuf1;

        // ---- issue X-frag loads (plain, cached) ----
        const half8* X8 = (const half8*)Xpk + ((size_t)t * 8 * 4 + bq4) * 64 + lane;
        half8 xf[8];
#pragma unroll
        for (int kc2 = 0; kc2 < 8; ++kc2) xf[kc2] = X8[kc2 * 256];

        // ---- issue 16 pipelined LLC loads for this WG's H slice ----
        const uint4v* Hsrc16 = (const uint4v*)Hin;
        uint4v tmp[16];
#pragma unroll
        for (int i = 0; i < 16; ++i) {
            int seq = i * 256 + tid;                  // 16B units, 4096 total
            int bqs = seq >> 11, kc = (seq >> 6) & 31, l2 = seq & 63;
            int off = (kc * 4 + bh * 2 + bqs) * 64 + l2;
            asm volatile("global_load_dwordx4 %0, %1, off sc0 sc1"
                         : "=v"(tmp[i]) : "v"(Hsrc16 + off));
        }
        asm volatile("s_waitcnt vmcnt(0)" ::: "memory");
#pragma unroll
        for (int i = 0; i < 16; ++i)
            Hld16[i * 256 + tid] = tmp[i];
        __syncthreads();   // H-LDS ready

        // ---- MFMA: D[16 rows = 4dim x 4gate][16 batches], K = 1280, 2 chains ----
        f32x4 acc0 = {0.f, 0.f, 0.f, 0.f};
        f32x4 acc1 = {0.f, 0.f, 0.f, 0.f};
#pragma unroll
        for (int kc = 0; kc < 32; ++kc) {
            half8 a  = Ald8[(t2 * 40 + kc) * 64 + lane];
            half8 bf = Hld8[(bql * 32 + kc) * 64 + lane];
            if (kc & 1)
                acc1 = __builtin_amdgcn_mfma_f32_16x16x32_f16(a, bf, acc1, 0, 0, 0);
            else
                acc0 = __builtin_amdgcn_mfma_f32_16x16x32_f16(a, bf, acc0, 0, 0, 0);
        }
#pragma unroll
        for (int kc2 = 0; kc2 < 8; ++kc2) {
            half8 a = Ald8[(t2 * 40 + 32 + kc2) * 64 + lane];
            if (kc2 & 1)
                acc1 = __builtin_amdgcn_mfma_f32_16x16x32_f16(a, xf[kc2], acc1, 0, 0, 0);
            else
                acc0 = __builtin_amdgcn_mfma_f32_16x16x32_f16(a, xf[kc2], acc0, 0, 0, 0);
        }

        // ---- gates fully in-register ----
        float pi = acc0[0] + acc1[0] + bsum[0];
        float pf = acc0[1] + acc1[1] + bsum[1];
        float pg = acc0[2] + acc1[2] + bsum[2];
        float po = acc0[3] + acc1[3] + bsum[3];
        float ig = sigmoidf_(pi), fg = sigmoidf_(pf);
        float gg = tanhf_(pg),    og = sigmoidf_(po);
        c_reg = fg * c_reg + ig * gg;
        float h = og * tanhf_(c_reg);
        h_last = h;

        // ---- publish h in B-frag layout (pack d-pairs via shfl, 4B LLC stores) ----
        float hp = __shfl_xor(h, 16);   // partner q^1 -> dim d^1
        if (!(q & 1)) {
            _Float16 h0 = (_Float16)h, h1 = (_Float16)hp;
            unsigned int pk = (unsigned int)__builtin_bit_cast(unsigned short, h0) |
                              ((unsigned int)__builtin_bit_cast(unsigned short, h1) << 16);
            size_t idx = ((size_t)(d >> 5) * 4 + (b >> 4)) * 512 +
                         ((d >> 3) & 3) * 128 + bl * 8 + (d & 7);
            asm volatile("global_store_dword %0, %1, off sc0 sc1"
                         :: "v"((unsigned int*)&Hout[idx]), "v"(pk) : "memory");
        }
        asm volatile("s_waitcnt vmcnt(0)" ::: "memory");   // drain this wave's stores
        __syncthreads();                                   // all waves drained

        if (t < TT_ - 1) {
            // ---- arrive: one 4B flag store per WG ----
            if (tid == 0) {
                int val = t + 1;
                asm volatile("global_store_dword %0, %1, off sc0 sc1"
                             :: "v"(flags + blockIdx.x), "v"(val) : "memory");
            }
            // ---- wave0 polls all 256 flags: 1 pipelined dwordx4 per lane ----
            if (w == 0) {
                const int* fp4 = flags + 4 * lane;
                for (;;) {
                    int4v fv;
                    asm volatile("global_load_dwordx4 %0, %1, off sc0 sc1\n\t"
                                 "s_waitcnt vmcnt(0)"
                                 : "=v"(fv) : "v"(fp4) : "memory");
                    int mn = min(min(fv.x, fv.y), min(fv.z, fv.w));
                    if (__all(mn >= t + 1)) break;
                    __builtin_amdgcn_s_sleep(4);
                }
            }
            __syncthreads();   // release all waves
        }
    }

    // ---- final state for decoder ----
    cT[d * 64 + b] = c_reg;
    hT[d * 64 + b] = h_last;
}

// ---------------- hdec = h_final @ dec_Whh^T + dec_bih + dec_bhh ----------------
__global__ __launch_bounds__(256)
void hdec_kernel(const float* __restrict__ hT, const float* __restrict__ Whh,
                 const float* __restrict__ bih, const float* __restrict__ bhh,
                 float* __restrict__ hdec)
{
    __shared__ float hb[1024];
    const int tid = threadIdx.x;
    const int b  = blockIdx.x >> 2;
    const int j0 = (blockIdx.x & 3) * 1024;
#pragma unroll
    for (int u = 0; u < 4; ++u) {
        int k = u * 256 + tid;
        hb[k] = hT[k * 64 + b];
    }
    __syncthreads();
#pragma unroll
    for (int rr = 0; rr < 4; ++rr) {
        int j = j0 + rr * 256 + tid;
        const float* wr = Whh + (size_t)j * HH;
        float a = bih[j] + bhh[j];
        for (int k = 0; k < 1024; k += 4) {
            float4 wv = *(const float4*)(wr + k);
            float4 hv = *(const float4*)&hb[k];
            a += hv.x * wv.x + hv.y * wv.y + hv.z * wv.z + hv.w * wv.w;
        }
        hdec[(size_t)b * G4 + j] = a;
    }
}

// ---------------- fused decoder: pre -> gates -> h_new -> FC ----------------
__global__ __launch_bounds__(256)
void dec_fused(const float* __restrict__ x, const float* __restrict__ Wih,
               const float* __restrict__ hdec, const float* __restrict__ cT,
               const float* __restrict__ fcW, const float* __restrict__ fcb,
               float* __restrict__ out)
{
    __shared__ __align__(16) float xs[16][256];              // 16 KB
    __shared__ __align__(16) __hip_bfloat16 ps[4][16][512];  // 64 KB
    const int tid = threadIdx.x;
    const int w  = blockIdx.x;
    const int b  = w >> 5;
    const int t0 = (w & 31) * 16;

#pragma unroll
    for (int u = 0; u < 16; ++u) {
        int e = u * 256 + tid;
        int tt = e >> 8, k = e & 255;
        xs[tt][k] = x[(size_t)b * (TT_ * IN_) + (size_t)(t0 + tt) * IN_ + k];
    }

    float facc[16];
#pragma unroll
    for (int tt = 0; tt < 16; ++tt) facc[tt] = fcb[tid];

    for (int dc = 0; dc < 2; ++dc) {
        __syncthreads();
        for (int q = 0; q < 4; ++q) {
            int ja = q * HH + dc * 512 + tid;
            int jb = ja + 256;
            float ha = hdec[(size_t)b * G4 + ja];
            float hb2 = hdec[(size_t)b * G4 + jb];
            float aa[16], ab[16];
#pragma unroll
            for (int tt = 0; tt < 16; ++tt) { aa[tt] = ha; ab[tt] = hb2; }
            const float* wa = Wih + (size_t)ja * IN_;
            const float* wb = Wih + (size_t)jb * IN_;
            for (int k = 0; k < 256; k += 4) {
                float4 va = *(const float4*)(wa + k);
                float4 vb = *(const float4*)(wb + k);
#pragma unroll
                for (int tt = 0; tt < 16; ++tt) {
                    float4 xv = *(const float4*)&xs[tt][k];
                    aa[tt] += xv.x * va.x + xv.y * va.y + xv.z * va.z + xv.w * va.w;
                    ab[tt] += xv.x * vb.x + xv.y * vb.y + xv.z * vb.z + xv.w * vb.w;
                }
            }
#pragma unroll
            for (int tt = 0; tt < 16; ++tt) {
                ps[q][tt][tid]       = __float2bfloat16(aa[tt]);
                ps[q][tt][tid + 256] = __float2bfloat16(ab[tt]);
            }
        }
        __syncthreads();

        float hn[32];
#pragma unroll
        for (int vv = 0; vv < 32; ++vv) {
            int p = vv * 256 + tid;
            int dl = p & 511, tt = p >> 9;
            float ig = __bfloat162float(ps[0][tt][dl]);
            float fg = __bfloat162float(ps[1][tt][dl]);
            float gg = __bfloat162float(ps[2][tt][dl]);
            float og = __bfloat162float(ps[3][tt][dl]);
            ig = sigmoidf_(ig); fg = sigmoidf_(fg);
            gg = tanhf_(gg);    og = sigmoidf_(og);
            float cv = cT[(dc * 512 + dl) * 64 + b];
            float cn = fg * cv + ig * gg;
            hn[vv] = og * tanhf_(cn);
        }
        __syncthreads();
        float* hnf = (float*)&ps[0][0][0];
#pragma unroll
        for (int vv = 0; vv < 32; ++vv) {
            int p = vv * 256 + tid;
            int dl = p & 511, tt = p >> 9;
            hnf[tt * 512 + dl] = hn[vv];
        }
        __syncthreads();

        const float* wo = fcW + (size_t)tid * HH + dc * 512;
        for (int k = 0; k < 512; k += 4) {
            float4 wv = *(const float4*)(wo + k);
#pragma unroll
            for (int tt = 0; tt < 16; ++tt) {
                float4 hv = *(const float4*)&hnf[tt * 512 + k];
                facc[tt] += hv.x * wv.x + hv.y * wv.y + hv.z * wv.z + hv.w * wv.w;
            }
        }
    }

#pragma unroll
    for (int tt = 0; tt < 16; ++tt) {
        out[(size_t)b * (TT_ * OO) + (size_t)(t0 + tt) * OO + tid] = facc[tt];
    }
}

extern "C" void kernel_launch(void* const* d_in, const int* in_sizes, int n_in,
                              void* d_out, int out_size, void* d_ws, size_t ws_size,
                              hipStream_t stream) {
    const float* x    = (const float*)d_in[0];
    const float* eWih = (const float*)d_in[1];
    const float* eWhh = (const float*)d_in[2];
    const float* ebih = (const float*)d_in[3];
    const float* ebhh = (const float*)d_in[4];
    const float* dWih = (const float*)d_in[5];
    const float* dWhh = (const float*)d_in[6];
    const float* dbih = (const float*)d_in[7];
    const float* dbhh = (const float*)d_in[8];
    const float* fcW  = (const float*)d_in[9];
    const float* fcb  = (const float*)d_in[10];

    // ws layout (f32 words): hT 65536 | cT 65536 | hdec 262144 | biasc 4096 |
    // flags 256 | fp16: Hf0 65536 | Hf1 65536 | Apk 5242880 | Xpk 8388608
    float* ws    = (float*)d_ws;
    float* hT    = ws;
    float* cT    = ws + 65536;
    float* hdec  = ws + 131072;
    float* biasc = ws + 393216;
    int*   flags = (int*)(ws + 397312);
    _Float16* fp  = (_Float16*)(ws + 397568);
    _Float16* Hf0 = fp;
    _Float16* Hf1 = fp + 65536;
    _Float16* Apk = fp + 131072;
    _Float16* Xpk = Apk + 5242880;

    pack_a2<<<dim3(2560), dim3(256), 0, stream>>>(eWhh, eWih, Apk);
    pack_x<<<dim3(4096), dim3(256), 0, stream>>>(x, Xpk);
    pack_bias<<<dim3(16), dim3(256), 0, stream>>>(ebih, ebhh, biasc);
    hipMemsetAsync(flags, 0, 256 * sizeof(int), stream);
    hipMemsetAsync(Hf0, 0, 65536 * sizeof(_Float16), stream);

    enc_persist<<<dim3(256), dim3(256), 0, stream>>>(
        Apk, Xpk, Hf0, Hf1, biasc, cT, hT, flags);

    hdec_kernel<<<dim3(256), dim3(256), 0, stream>>>(hT, dWhh, dbih, dbhh, hdec);
    dec_fused<<<dim3(2048), dim3(256), 0, stream>>>(x, dWih, hdec, cT, fcW, fcb,
                                                    (float*)d_out);
}

// Round 7
// 3902.844 us; speedup vs baseline: 2.9798x; 1.6957x over previous
//
#include <hip/hip_runtime.h>
#include <hip/hip_bf16.h>

#define BB 64
#define TT_ 512
#define IN_ 256
#define HH 1024
#define G4 4096
#define OO 256

typedef _Float16 half8 __attribute__((ext_vector_type(8)));
typedef float f32x4 __attribute__((ext_vector_type(4)));
typedef unsigned int uint4v __attribute__((ext_vector_type(4)));
typedef int int4v __attribute__((ext_vector_type(4)));

__device__ __forceinline__ float sigmoidf_(float v) {
    return 1.f / (1.f + __expf(-v));
}
__device__ __forceinline__ float tanhf_(float v) {
    float vc = fminf(fmaxf(v, -15.f), 15.f);
    float e = __expf(2.f * vc);
    return (e - 1.f) / (e + 1.f);
}

// ---------------- encoder weight pack ----------------
// Apk[dq(128)][t2(2)][kc(40)][lane(64)][e(8)] fp16.
// A-tile rows: rD = ddl*4 + g, so MFMA acc[r] of lane q=l>>4 holds gate r of
// dim dq*8 + t2*4 + q -> gates fused in-register.
__global__ __launch_bounds__(256)
void pack_a2(const float* __restrict__ Whh, const float* __restrict__ Wih,
             _Float16* __restrict__ Apk)
{
    int id = blockIdx.x * 256 + threadIdx.x;      // 16B-unit id < 655360
    int dq  = id / 5120;
    int r1  = id - dq * 5120;
    int t2  = r1 / 2560;
    int r2  = r1 - t2 * 2560;
    int kc  = r2 >> 6, l = r2 & 63;
    int rD  = l & 15;
    int g   = rD & 3, ddl = rD >> 2;
    int d   = dq * 8 + t2 * 4 + ddl;
    int j   = g * HH + d;
    int k0  = kc * 32 + ((l >> 4) << 3);
    half8 v;
    if (kc < 32) {
        const float* s = Whh + (size_t)j * HH + k0;
#pragma unroll
        for (int e = 0; e < 8; ++e) v[e] = (_Float16)s[e];
    } else {
        const float* s = Wih + (size_t)j * IN_ + (k0 - 1024);
#pragma unroll
        for (int e = 0; e < 8; ++e) v[e] = (_Float16)s[e];
    }
    ((half8*)Apk)[id] = v;
}

// ---------------- decoder weight pack: Adecpk[dq(128)][t2(2)][kc2(8)][lane][e8] ----------------
__global__ __launch_bounds__(256)
void pack_adec(const float* __restrict__ Wih, _Float16* __restrict__ Adecpk)
{
    int id = blockIdx.x * 256 + threadIdx.x;      // < 131072
    int dq = id >> 10;
    int r1 = id & 1023;
    int t2 = r1 >> 9;
    int r2 = r1 & 511;
    int kc2 = r2 >> 6, l = r2 & 63;
    int rD = l & 15, g = rD & 3, ddl = rD >> 2;
    int d  = dq * 8 + t2 * 4 + ddl;
    int j  = g * HH + d;
    int k0 = kc2 * 32 + ((l >> 4) << 3);
    const float* s = Wih + (size_t)j * IN_ + k0;
    half8 v;
#pragma unroll
    for (int e = 0; e < 8; ++e) v[e] = (_Float16)s[e];
    ((half8*)Adecpk)[id] = v;
}

// ---------------- FC weight pack: fcWpk[ot(16)][kc(32)][lane][e8] ----------------
__global__ __launch_bounds__(256)
void pack_fcw(const float* __restrict__ fcW, _Float16* __restrict__ fcWpk)
{
    int id = blockIdx.x * 256 + threadIdx.x;      // < 32768
    int ot = id >> 11;
    int r  = id & 2047;
    int kc = r >> 6, l = r & 63;
    int o  = ot * 16 + (l & 15);
    int k0 = kc * 32 + ((l >> 4) << 3);
    const float* s = fcW + (size_t)o * HH + k0;
    half8 v;
#pragma unroll
    for (int e = 0; e < 8; ++e) v[e] = (_Float16)s[e];
    ((half8*)fcWpk)[id] = v;
}

// ---------------- x pack: fp16 B-fragment-major per t ----------------
__global__ __launch_bounds__(256)
void pack_x(const float* __restrict__ x, _Float16* __restrict__ Xpk)
{
    int id = blockIdx.x * 256 + threadIdx.x;  // < 1048576
    int l = id & 63, bt = (id >> 6) & 3, kc2 = (id >> 8) & 7, t = id >> 11;
    int b  = bt * 16 + (l & 15);
    int i0 = kc2 * 32 + ((l >> 4) << 3);
    const float* s = x + ((size_t)b * TT_ + t) * IN_ + i0;
    half8 v;
#pragma unroll
    for (int e = 0; e < 8; ++e) v[e] = (_Float16)s[e];
    ((half8*)Xpk)[id] = v;
}

__global__ __launch_bounds__(256)
void pack_bias(const float* __restrict__ bih, const float* __restrict__ bhh,
               float* __restrict__ biasc)
{
    int j = blockIdx.x * 256 + threadIdx.x;
    if (j < G4) biasc[j] = bih[j] + bhh[j];
}

// ---------------- persistent encoder (unchanged from R6 except s_sleep) ----------------
__global__ __launch_bounds__(256, 1)
void enc_persist(const _Float16* __restrict__ Apk,
                 const _Float16* __restrict__ Xpk,
                 _Float16* __restrict__ Hbuf0,
                 _Float16* __restrict__ Hbuf1,
                 const float* __restrict__ biasc,
                 float* __restrict__ cT,
                 float* __restrict__ hT,
                 int* __restrict__ flags)
{
    __shared__ __align__(16) _Float16 Alds[2 * 40 * 64 * 8];   // 80 KB
    __shared__ __align__(16) _Float16 Hlds[2 * 32 * 64 * 8];   // 64 KB
    const int tid  = threadIdx.x;
    const int lane = tid & 63, w = tid >> 6;
    const int t2 = w >> 1, bql = w & 1;
    const int dq = blockIdx.x >> 1, bh = blockIdx.x & 1;
    const int q  = lane >> 4, bl = lane & 15;
    const int d  = dq * 8 + t2 * 4 + q;
    const int b  = bh * 32 + bql * 16 + bl;
    const int bq4 = bh * 2 + bql;

    const half8* Asrc = (const half8*)Apk + (size_t)dq * 5120;
    half8* Ald8 = (half8*)Alds;
#pragma unroll
    for (int i = 0; i < 20; ++i)
        Ald8[i * 256 + tid] = Asrc[i * 256 + tid];

    float bsum[4];
#pragma unroll
    for (int g2 = 0; g2 < 4; ++g2) bsum[g2] = biasc[g2 * HH + d];

    const half8* Hld8 = (const half8*)Hlds;
    uint4v* Hld16 = (uint4v*)Hlds;

    float c_reg = 0.f, h_last = 0.f;
    __syncthreads();

    for (int t = 0; t < TT_; ++t) {
        const _Float16* Hin = (t & 1) ? Hbuf1 : Hbuf0;
        _Float16* Hout      = (t & 1) ? Hbuf0 : Hbuf1;

        const half8* X8 = (const half8*)Xpk + ((size_t)t * 8 * 4 + bq4) * 64 + lane;
        half8 xf[8];
#pragma unroll
        for (int kc2 = 0; kc2 < 8; ++kc2) xf[kc2] = X8[kc2 * 256];

        const uint4v* Hsrc16 = (const uint4v*)Hin;
        uint4v tmp[16];
#pragma unroll
        for (int i = 0; i < 16; ++i) {
            int seq = i * 256 + tid;
            int bqs = seq >> 11, kc = (seq >> 6) & 31, l2 = seq & 63;
            int off = (kc * 4 + bh * 2 + bqs) * 64 + l2;
            asm volatile("global_load_dwordx4 %0, %1, off sc0 sc1"
                         : "=v"(tmp[i]) : "v"(Hsrc16 + off));
        }
        asm volatile("s_waitcnt vmcnt(0)" ::: "memory");
#pragma unroll
        for (int i = 0; i < 16; ++i)
            Hld16[i * 256 + tid] = tmp[i];
        __syncthreads();

        f32x4 acc0 = {0.f, 0.f, 0.f, 0.f};
        f32x4 acc1 = {0.f, 0.f, 0.f, 0.f};
#pragma unroll
        for (int kc = 0; kc < 32; ++kc) {
            half8 a  = Ald8[(t2 * 40 + kc) * 64 + lane];
            half8 bf = Hld8[(bql * 32 + kc) * 64 + lane];
            if (kc & 1)
                acc1 = __builtin_amdgcn_mfma_f32_16x16x32_f16(a, bf, acc1, 0, 0, 0);
            else
                acc0 = __builtin_amdgcn_mfma_f32_16x16x32_f16(a, bf, acc0, 0, 0, 0);
        }
#pragma unroll
        for (int kc2 = 0; kc2 < 8; ++kc2) {
            half8 a = Ald8[(t2 * 40 + 32 + kc2) * 64 + lane];
            if (kc2 & 1)
                acc1 = __builtin_amdgcn_mfma_f32_16x16x32_f16(a, xf[kc2], acc1, 0, 0, 0);
            else
                acc0 = __builtin_amdgcn_mfma_f32_16x16x32_f16(a, xf[kc2], acc0, 0, 0, 0);
        }

        float pi = acc0[0] + acc1[0] + bsum[0];
        float pf = acc0[1] + acc1[1] + bsum[1];
        float pg = acc0[2] + acc1[2] + bsum[2];
        float po = acc0[3] + acc1[3] + bsum[3];
        float ig = sigmoidf_(pi), fg = sigmoidf_(pf);
        float gg = tanhf_(pg),    og = sigmoidf_(po);
        c_reg = fg * c_reg + ig * gg;
        float h = og * tanhf_(c_reg);
        h_last = h;

        float hp = __shfl_xor(h, 16);
        if (!(q & 1)) {
            _Float16 h0 = (_Float16)h, h1 = (_Float16)hp;
            unsigned int pk = (unsigned int)__builtin_bit_cast(unsigned short, h0) |
                              ((unsigned int)__builtin_bit_cast(unsigned short, h1) << 16);
            size_t idx = ((size_t)(d >> 5) * 4 + (b >> 4)) * 512 +
                         ((d >> 3) & 3) * 128 + bl * 8 + (d & 7);
            asm volatile("global_store_dword %0, %1, off sc0 sc1"
                         :: "v"((unsigned int*)&Hout[idx]), "v"(pk) : "memory");
        }
        asm volatile("s_waitcnt vmcnt(0)" ::: "memory");
        __syncthreads();

        if (t < TT_ - 1) {
            if (tid == 0) {
                int val = t + 1;
                asm volatile("global_store_dword %0, %1, off sc0 sc1"
                             :: "v"(flags + blockIdx.x), "v"(val) : "memory");
            }
            if (w == 0) {
                const int* fp4 = flags + 4 * lane;
                for (;;) {
                    int4v fv;
                    asm volatile("global_load_dwordx4 %0, %1, off sc0 sc1\n\t"
                                 "s_waitcnt vmcnt(0)"
                                 : "=v"(fv) : "v"(fp4) : "memory");
                    int mn = min(min(fv.x, fv.y), min(fv.z, fv.w));
                    if (__all(mn >= t + 1)) break;
                    __builtin_amdgcn_s_sleep(1);
                }
            }
            __syncthreads();
        }
    }

    cT[d * 64 + b] = c_reg;
    hT[d * 64 + b] = h_last;
}

// ---------------- hdecg = h_final @ dec_Whh^T + dec_bih + dec_bhh ----------------
// writes gate-major layout hdecg[g(4)][d(1024)][b(64)]
__global__ __launch_bounds__(256)
void hdec_kernel(const float* __restrict__ hT, const float* __restrict__ Whh,
                 const float* __restrict__ bih, const float* __restrict__ bhh,
                 float* __restrict__ hdecg)
{
    __shared__ float hb[1024];
    const int tid = threadIdx.x;
    const int b  = blockIdx.x >> 2;
    const int j0 = (blockIdx.x & 3) * 1024;
#pragma unroll
    for (int u = 0; u < 4; ++u) {
        int k = u * 256 + tid;
        hb[k] = hT[k * 64 + b];
    }
    __syncthreads();
#pragma unroll
    for (int rr = 0; rr < 4; ++rr) {
        int j = j0 + rr * 256 + tid;
        const float* wr = Whh + (size_t)j * HH;
        float a = bih[j] + bhh[j];
        for (int k = 0; k < 1024; k += 4) {
            float4 wv = *(const float4*)(wr + k);
            float4 hv = *(const float4*)&hb[k];
            a += hv.x * wv.x + hv.y * wv.y + hv.z * wv.z + hv.w * wv.w;
        }
        hdecg[((size_t)(j >> 10) * 1024 + (j & 1023)) * 64 + b] = a;
    }
}

// ---------------- MFMA decoder: pre-GEMM -> gates -> FC, fused ----------------
// grid 2048 = (t = bid>>2, bq4 = bid&3), block 256 (4 waves).
// Wave w: pre for dq in [w*32, w*32+32) (4-gate A-tiles -> gates in-register),
// h_new staged to LDS in B-frag layout, then FC for ot in [w*4, w*4+4).
__global__ __launch_bounds__(256)
void dec_mfma(const _Float16* __restrict__ Adecpk,
              const _Float16* __restrict__ fcWpk,
              const _Float16* __restrict__ Xpk,
              const float* __restrict__ hdecg,
              const float* __restrict__ cT,
              const float* __restrict__ fcb,
              float* __restrict__ out)
{
    __shared__ __align__(16) _Float16 Hn[32 * 64 * 8];   // 32 KB  B-frags [kc][lane][e]
    __shared__ __align__(16) float outl[16][260];        // ~16.6 KB
    const int tid = threadIdx.x;
    const int lane = tid & 63, w = tid >> 6;
    const int t = blockIdx.x >> 2, bq4 = blockIdx.x & 3;
    const int q = lane >> 4, bl = lane & 15;
    const int bg = bq4 * 16 + bl;

    // x B-frags (shared across all dq)
    const half8* X8 = (const half8*)Xpk + ((size_t)t * 32 + bq4) * 64 + lane;
    half8 xf[8];
#pragma unroll
    for (int kc2 = 0; kc2 < 8; ++kc2) xf[kc2] = X8[kc2 * 256];

    const half8* AD = (const half8*)Adecpk + lane;
    for (int dqi = 0; dqi < 32; ++dqi) {
        int dq = w * 32 + dqi;
#pragma unroll
        for (int t2 = 0; t2 < 2; ++t2) {
            f32x4 acc = {0.f, 0.f, 0.f, 0.f};
#pragma unroll
            for (int kc2 = 0; kc2 < 8; ++kc2) {
                half8 a = AD[((size_t)(dq * 2 + t2) * 8 + kc2) * 64];
                acc = __builtin_amdgcn_mfma_f32_16x16x32_f16(a, xf[kc2], acc, 0, 0, 0);
            }
            int d = dq * 8 + t2 * 4 + q;
            float cv = cT[d * 64 + bg];
            float pi = acc[0] + hdecg[(size_t)(0 * HH + d) * 64 + bg];
            float pf = acc[1] + hdecg[(size_t)(1 * HH + d) * 64 + bg];
            float pg = acc[2] + hdecg[(size_t)(2 * HH + d) * 64 + bg];
            float po = acc[3] + hdecg[(size_t)(3 * HH + d) * 64 + bg];
            float ig = sigmoidf_(pi), fg = sigmoidf_(pf);
            float gg = tanhf_(pg),    og = sigmoidf_(po);
            float cn = fg * cv + ig * gg;
            float h = og * tanhf_(cn);
            // B-frag position: kc=d>>5, lane'=((d>>3)&3)*16+bl, e=d&7
            Hn[((d >> 5) * 64 + ((d >> 3) & 3) * 16 + bl) * 8 + (d & 7)] = (_Float16)h;
        }
    }
    __syncthreads();

    // FC: out[o, b] for ot in wave's range, K=1024 over LDS B-frags
    const half8* Hn8 = (const half8*)Hn + lane;
    const half8* FW = (const half8*)fcWpk + lane;
#pragma unroll
    for (int oti = 0; oti < 4; ++oti) {
        int ot = w * 4 + oti;
        f32x4 acc = {0.f, 0.f, 0.f, 0.f};
        for (int kc = 0; kc < 32; ++kc) {
            half8 a  = FW[((size_t)ot * 32 + kc) * 64];
            half8 bf = Hn8[kc * 64];
            acc = __builtin_amdgcn_mfma_f32_16x16x32_f16(a, bf, acc, 0, 0, 0);
        }
#pragma unroll
        for (int r = 0; r < 4; ++r) {
            int o = ot * 16 + q * 4 + r;
            outl[bl][o] = acc[r] + fcb[o];
        }
    }
    __syncthreads();

    // coalesced writeout: 16 (b) rows x 256 o
#pragma unroll
    for (int i = 0; i < 16; ++i) {
        int b = bq4 * 16 + i;
        out[((size_t)b * TT_ + t) * OO + tid] = outl[i][tid];
    }
}

extern "C" void kernel_launch(void* const* d_in, const int* in_sizes, int n_in,
                              void* d_out, int out_size, void* d_ws, size_t ws_size,
                              hipStream_t stream) {
    const float* x    = (const float*)d_in[0];
    const float* eWih = (const float*)d_in[1];
    const float* eWhh = (const float*)d_in[2];
    const float* ebih = (const float*)d_in[3];
    const float* ebhh = (const float*)d_in[4];
    const float* dWih = (const float*)d_in[5];
    const float* dWhh = (const float*)d_in[6];
    const float* dbih = (const float*)d_in[7];
    const float* dbhh = (const float*)d_in[8];
    const float* fcW  = (const float*)d_in[9];
    const float* fcb  = (const float*)d_in[10];

    // ws layout (f32 words): hT 65536 | cT 65536 | hdecg 262144 | biasc 4096 |
    // flags 256 | fp16: Hf0 65536 | Hf1 65536 | Apk 5242880 | Xpk 8388608 |
    // Adecpk 1048576 | fcWpk 262144   (~30.3 MB total)
    float* ws    = (float*)d_ws;
    float* hT    = ws;
    float* cT    = ws + 65536;
    float* hdecg = ws + 131072;
    float* biasc = ws + 393216;
    int*   flags = (int*)(ws + 397312);
    _Float16* fp  = (_Float16*)(ws + 397568);
    _Float16* Hf0 = fp;
    _Float16* Hf1 = fp + 65536;
    _Float16* Apk = fp + 131072;
    _Float16* Xpk = Apk + 5242880;
    _Float16* Adecpk = Xpk + 8388608;
    _Float16* fcWpk  = Adecpk + 1048576;

    pack_a2<<<dim3(2560), dim3(256), 0, stream>>>(eWhh, eWih, Apk);
    pack_x<<<dim3(4096), dim3(256), 0, stream>>>(x, Xpk);
    pack_bias<<<dim3(16), dim3(256), 0, stream>>>(ebih, ebhh, biasc);
    pack_adec<<<dim3(512), dim3(256), 0, stream>>>(dWih, Adecpk);
    pack_fcw<<<dim3(128), dim3(256), 0, stream>>>(fcW, fcWpk);
    hipMemsetAsync(flags, 0, 256 * sizeof(int), stream);
    hipMemsetAsync(Hf0, 0, 65536 * sizeof(_Float16), stream);

    enc_persist<<<dim3(256), dim3(256), 0, stream>>>(
        Apk, Xpk, Hf0, Hf1, biasc, cT, hT, flags);

    hdec_kernel<<<dim3(256), dim3(256), 0, stream>>>(hT, dWhh, dbih, dbhh, hdecg);
    dec_mfma<<<dim3(2048), dim3(256), 0, stream>>>(Adecpk, fcWpk, Xpk, hdecg, cT,
                                                   fcb, (float*)d_out);
}

// Round 8
// 2861.301 us; speedup vs baseline: 4.0645x; 1.3640x over previous
//
#include <hip/hip_runtime.h>
#include <hip/hip_bf16.h>

#define BB 64
#define TT_ 512
#define IN_ 256
#define HH 1024
#define G4 4096
#define OO 256

typedef _Float16 half8 __attribute__((ext_vector_type(8)));
typedef float f32x4 __attribute__((ext_vector_type(4)));
typedef unsigned int uint4v __attribute__((ext_vector_type(4)));
typedef int int4v __attribute__((ext_vector_type(4)));

__device__ __forceinline__ float sigmoidf_(float v) {
    return 1.f / (1.f + __expf(-v));
}
__device__ __forceinline__ float tanhf_(float v) {
    float vc = fminf(fmaxf(v, -15.f), 15.f);
    float e = __expf(2.f * vc);
    return (e - 1.f) / (e + 1.f);
}

// ---------------- encoder weight pack (unchanged layout) ----------------
// Apk[jt(256)][kc(40)][lane(64)][e(8)] fp16, jt = tile of 4 dims x 4 gates.
// Tile rows rD = ddl*4 + g -> dims jt*4+ddl; MFMA acc[r] of lane q holds
// gate r of dim jt*4 + q. kc 0..31 = Whh K, kc 32..39 = Wih K.
__global__ __launch_bounds__(256)
void pack_a2(const float* __restrict__ Whh, const float* __restrict__ Wih,
             _Float16* __restrict__ Apk)
{
    int id = blockIdx.x * 256 + threadIdx.x;      // 16B-unit id < 655360
    int dq  = id / 5120;
    int r1  = id - dq * 5120;
    int t2  = r1 / 2560;
    int r2  = r1 - t2 * 2560;
    int kc  = r2 >> 6, l = r2 & 63;
    int rD  = l & 15;
    int g   = rD & 3, ddl = rD >> 2;
    int d   = dq * 8 + t2 * 4 + ddl;
    int j   = g * HH + d;
    int k0  = kc * 32 + ((l >> 4) << 3);
    half8 v;
    if (kc < 32) {
        const float* s = Whh + (size_t)j * HH + k0;
#pragma unroll
        for (int e = 0; e < 8; ++e) v[e] = (_Float16)s[e];
    } else {
        const float* s = Wih + (size_t)j * IN_ + (k0 - 1024);
#pragma unroll
        for (int e = 0; e < 8; ++e) v[e] = (_Float16)s[e];
    }
    ((half8*)Apk)[id] = v;
}

// ---------------- decoder weight pack ----------------
__global__ __launch_bounds__(256)
void pack_adec(const float* __restrict__ Wih, _Float16* __restrict__ Adecpk)
{
    int id = blockIdx.x * 256 + threadIdx.x;      // < 131072
    int dq = id >> 10;
    int r1 = id & 1023;
    int t2 = r1 >> 9;
    int r2 = r1 & 511;
    int kc2 = r2 >> 6, l = r2 & 63;
    int rD = l & 15, g = rD & 3, ddl = rD >> 2;
    int d  = dq * 8 + t2 * 4 + ddl;
    int j  = g * HH + d;
    int k0 = kc2 * 32 + ((l >> 4) << 3);
    const float* s = Wih + (size_t)j * IN_ + k0;
    half8 v;
#pragma unroll
    for (int e = 0; e < 8; ++e) v[e] = (_Float16)s[e];
    ((half8*)Adecpk)[id] = v;
}

// ---------------- FC weight pack ----------------
__global__ __launch_bounds__(256)
void pack_fcw(const float* __restrict__ fcW, _Float16* __restrict__ fcWpk)
{
    int id = blockIdx.x * 256 + threadIdx.x;      // < 32768
    int ot = id >> 11;
    int r  = id & 2047;
    int kc = r >> 6, l = r & 63;
    int o  = ot * 16 + (l & 15);
    int k0 = kc * 32 + ((l >> 4) << 3);
    const float* s = fcW + (size_t)o * HH + k0;
    half8 v;
#pragma unroll
    for (int e = 0; e < 8; ++e) v[e] = (_Float16)s[e];
    ((half8*)fcWpk)[id] = v;
}

// ---------------- x pack ----------------
__global__ __launch_bounds__(256)
void pack_x(const float* __restrict__ x, _Float16* __restrict__ Xpk)
{
    int id = blockIdx.x * 256 + threadIdx.x;  // < 1048576
    int l = id & 63, bt = (id >> 6) & 3, kc2 = (id >> 8) & 7, t = id >> 11;
    int b  = bt * 16 + (l & 15);
    int i0 = kc2 * 32 + ((l >> 4) << 3);
    const float* s = x + ((size_t)b * TT_ + t) * IN_ + i0;
    half8 v;
#pragma unroll
    for (int e = 0; e < 8; ++e) v[e] = (_Float16)s[e];
    ((half8*)Xpk)[id] = v;
}

__global__ __launch_bounds__(256)
void pack_bias(const float* __restrict__ bih, const float* __restrict__ bhh,
               float* __restrict__ biasc)
{
    int j = blockIdx.x * 256 + threadIdx.x;
    if (j < G4) biasc[j] = bih[j] + bhh[j];
}

// ---------------- persistent encoder v4: batch-partitioned groups ----------------
// grid 256 = (dq16 = bid>>2 in [0,64), bq4 = bid&3). 4 independent groups of
// 16 batches x 64 WGs; per-group 64-wide flag barrier. WG = 16 dims x 4 gates
// x 16 batches; wave t4 = one 16-row tile (4 dims x 4 gates). Whh in LDS
// (128KB, once), Wih A-frags in registers (8 frags), H slice 32KB staged to
// LDS per step via pipelined sc0sc1 loads. Gates fused in-register.
__global__ __launch_bounds__(256, 1)
void enc_persist(const _Float16* __restrict__ Apk,
                 const _Float16* __restrict__ Xpk,
                 _Float16* __restrict__ Hbuf0,
                 _Float16* __restrict__ Hbuf1,
                 const float* __restrict__ biasc,
                 float* __restrict__ cT,
                 float* __restrict__ hT,
                 int* __restrict__ flags)
{
    __shared__ __align__(16) _Float16 Ald[4 * 32 * 64 * 8];   // 128 KB
    __shared__ __align__(16) _Float16 Hst[32 * 64 * 8];       // 32 KB
    const int tid  = threadIdx.x;
    const int lane = tid & 63, t4 = tid >> 6;
    const int dq16 = blockIdx.x >> 2, bq4 = blockIdx.x & 3;
    const int q = lane >> 4, bl = lane & 15;
    const int d = dq16 * 16 + t4 * 4 + q;        // this thread's dim
    const int b = bq4 * 16 + bl;                 // this thread's batch
    const int jt = dq16 * 4 + t4;                // this wave's A-tile

    // ---- one-time: Whh A-frags -> LDS (per wave: its tile's 32 kc) ----
    {
        const half8* src = (const half8*)Apk + ((size_t)jt * 40) * 64 + lane;
        half8* dst = (half8*)Ald + (size_t)t4 * 32 * 64 + lane;
#pragma unroll
        for (int kc = 0; kc < 32; ++kc) dst[kc * 64] = src[kc * 64];
    }
    // ---- one-time: Wih A-frags -> registers (8 frags, static idx) ----
    half8 xa[8];
    {
        const half8* src = (const half8*)Apk + ((size_t)jt * 40 + 32) * 64 + lane;
#pragma unroll
        for (int k = 0; k < 8; ++k) xa[k] = src[k * 64];
    }

    float bsum[4];
#pragma unroll
    for (int g = 0; g < 4; ++g) bsum[g] = biasc[g * HH + d];

    const half8* Ald8 = (const half8*)Ald + (size_t)t4 * 32 * 64 + lane;
    const half8* Hld8 = (const half8*)Hst + lane;
    uint4v* Hst16 = (uint4v*)Hst;

    float c_reg = 0.f, h_last = 0.f;
    __syncthreads();   // A-LDS ready

    for (int t = 0; t < TT_; ++t) {
        const _Float16* Hin = (t & 1) ? Hbuf1 : Hbuf0;
        _Float16* Hout      = (t & 1) ? Hbuf0 : Hbuf1;

        // ---- issue H loads (group slice 32KB, 8 x dwordx4/thread, LLC) ----
        const uint4v* Hsrc = (const uint4v*)Hin + (size_t)bq4 * 2048;
        uint4v tmp[8];
#pragma unroll
        for (int i = 0; i < 8; ++i) {
            asm volatile("global_load_dwordx4 %0, %1, off sc0 sc1"
                         : "=v"(tmp[i]) : "v"(Hsrc + i * 256 + tid));
        }
        // ---- X B-frags (plain cached loads, hide under H latency) ----
        const half8* X8 = (const half8*)Xpk + ((size_t)t * 32 + bq4) * 64 + lane;
        half8 xf[8];
#pragma unroll
        for (int k = 0; k < 8; ++k) xf[k] = X8[k * 256];

        asm volatile("s_waitcnt vmcnt(0)" ::: "memory");
#pragma unroll
        for (int i = 0; i < 8; ++i) Hst16[i * 256 + tid] = tmp[i];
        __syncthreads();   // H-LDS ready

        // ---- MFMA: 32 H-kc (LDS) + 8 X-kc (regs), 4 acc chains ----
        f32x4 acc[4];
#pragma unroll
        for (int i = 0; i < 4; ++i) acc[i] = (f32x4){0.f, 0.f, 0.f, 0.f};
#pragma unroll
        for (int kc = 0; kc < 32; ++kc) {
            half8 a  = Ald8[kc * 64];
            half8 bf = Hld8[kc * 64];
            acc[kc & 3] = __builtin_amdgcn_mfma_f32_16x16x32_f16(a, bf, acc[kc & 3], 0, 0, 0);
        }
#pragma unroll
        for (int k = 0; k < 8; ++k)
            acc[k & 3] = __builtin_amdgcn_mfma_f32_16x16x32_f16(xa[k], xf[k], acc[k & 3], 0, 0, 0);

        // ---- gates fully in-register: acc[*][r] sums = gate r of dim d ----
        float pi = acc[0][0] + acc[1][0] + acc[2][0] + acc[3][0] + bsum[0];
        float pf = acc[0][1] + acc[1][1] + acc[2][1] + acc[3][1] + bsum[1];
        float pg = acc[0][2] + acc[1][2] + acc[2][2] + acc[3][2] + bsum[2];
        float po = acc[0][3] + acc[1][3] + acc[2][3] + acc[3][3] + bsum[3];
        float ig = sigmoidf_(pi), fg = sigmoidf_(pf);
        float gg = tanhf_(pg),    og = sigmoidf_(po);
        c_reg = fg * c_reg + ig * gg;
        float h = og * tanhf_(c_reg);
        h_last = h;

        // ---- publish h into group B-frag slice (pair dims via shfl, 4B) ----
        float hp = __shfl_xor(h, 16);    // partner q^1 -> dim d^1
        if (!(q & 1)) {
            _Float16 h0 = (_Float16)h, h1 = (_Float16)hp;
            unsigned int pk = (unsigned int)__builtin_bit_cast(unsigned short, h0) |
                              ((unsigned int)__builtin_bit_cast(unsigned short, h1) << 16);
            unsigned int idx = ((unsigned)bq4 * 2048 + ((unsigned)d >> 5) * 64 +
                                (((unsigned)d >> 3) & 3) * 16 + bl) * 8 + (d & 7);
            asm volatile("global_store_dword %0, %1, off sc0 sc1"
                         :: "v"((unsigned int*)&Hout[idx]), "v"(pk) : "memory");
        }
        asm volatile("s_waitcnt vmcnt(0)" ::: "memory");   // drain this wave's stores
        __syncthreads();                                   // all waves drained

        if (t < TT_ - 1) {
            // ---- arrive: group-local flag ----
            if (tid == 0) {
                int val = t + 1;
                asm volatile("global_store_dword %0, %1, off sc0 sc1"
                             :: "v"(flags + bq4 * 64 + dq16), "v"(val) : "memory");
            }
            // ---- wave0 polls the group's 64 flags (lanes 0..15 x dwordx4) ----
            if (t4 == 0) {
                const int* fp4 = flags + bq4 * 64 + (lane & 15) * 4;
                for (;;) {
                    int4v fv;
                    asm volatile("global_load_dwordx4 %0, %1, off sc0 sc1\n\t"
                                 "s_waitcnt vmcnt(0)"
                                 : "=v"(fv) : "v"(fp4) : "memory");
                    int mn = min(min(fv.x, fv.y), min(fv.z, fv.w));
                    if (__all(mn >= t + 1)) break;
                    __builtin_amdgcn_s_sleep(1);
                }
            }
            __syncthreads();   // release all waves
        }
    }

    // ---- final state for decoder ----
    cT[d * 64 + b] = c_reg;
    hT[d * 64 + b] = h_last;
}

// ---------------- hdecg = h_final @ dec_Whh^T + biases (gate-major out) ----------------
__global__ __launch_bounds__(256)
void hdec_kernel(const float* __restrict__ hT, const float* __restrict__ Whh,
                 const float* __restrict__ bih, const float* __restrict__ bhh,
                 float* __restrict__ hdecg)
{
    __shared__ float hb[1024];
    const int tid = threadIdx.x;
    const int b  = blockIdx.x >> 2;
    const int j0 = (blockIdx.x & 3) * 1024;
#pragma unroll
    for (int u = 0; u < 4; ++u) {
        int k = u * 256 + tid;
        hb[k] = hT[k * 64 + b];
    }
    __syncthreads();
#pragma unroll
    for (int rr = 0; rr < 4; ++rr) {
        int j = j0 + rr * 256 + tid;
        const float* wr = Whh + (size_t)j * HH;
        float a = bih[j] + bhh[j];
        for (int k = 0; k < 1024; k += 4) {
            float4 wv = *(const float4*)(wr + k);
            float4 hv = *(const float4*)&hb[k];
            a += hv.x * wv.x + hv.y * wv.y + hv.z * wv.z + hv.w * wv.w;
        }
        hdecg[((size_t)(j >> 10) * 1024 + (j & 1023)) * 64 + b] = a;
    }
}

// ---------------- MFMA decoder (unchanged) ----------------
__global__ __launch_bounds__(256)
void dec_mfma(const _Float16* __restrict__ Adecpk,
              const _Float16* __restrict__ fcWpk,
              const _Float16* __restrict__ Xpk,
              const float* __restrict__ hdecg,
              const float* __restrict__ cT,
              const float* __restrict__ fcb,
              float* __restrict__ out)
{
    __shared__ __align__(16) _Float16 Hn[32 * 64 * 8];   // 32 KB
    __shared__ __align__(16) float outl[16][260];
    const int tid = threadIdx.x;
    const int lane = tid & 63, w = tid >> 6;
    const int t = blockIdx.x >> 2, bq4 = blockIdx.x & 3;
    const int q = lane >> 4, bl = lane & 15;
    const int bg = bq4 * 16 + bl;

    const half8* X8 = (const half8*)Xpk + ((size_t)t * 32 + bq4) * 64 + lane;
    half8 xf[8];
#pragma unroll
    for (int kc2 = 0; kc2 < 8; ++kc2) xf[kc2] = X8[kc2 * 256];

    const half8* AD = (const half8*)Adecpk + lane;
    for (int dqi = 0; dqi < 32; ++dqi) {
        int dq = w * 32 + dqi;
#pragma unroll
        for (int t2 = 0; t2 < 2; ++t2) {
            f32x4 acc = {0.f, 0.f, 0.f, 0.f};
#pragma unroll
            for (int kc2 = 0; kc2 < 8; ++kc2) {
                half8 a = AD[((size_t)(dq * 2 + t2) * 8 + kc2) * 64];
                acc = __builtin_amdgcn_mfma_f32_16x16x32_f16(a, xf[kc2], acc, 0, 0, 0);
            }
            int d = dq * 8 + t2 * 4 + q;
            float cv = cT[d * 64 + bg];
            float pi = acc[0] + hdecg[(size_t)(0 * HH + d) * 64 + bg];
            float pf = acc[1] + hdecg[(size_t)(1 * HH + d) * 64 + bg];
            float pg = acc[2] + hdecg[(size_t)(2 * HH + d) * 64 + bg];
            float po = acc[3] + hdecg[(size_t)(3 * HH + d) * 64 + bg];
            float ig = sigmoidf_(pi), fg = sigmoidf_(pf);
            float gg = tanhf_(pg),    og = sigmoidf_(po);
            float cn = fg * cv + ig * gg;
            float h = og * tanhf_(cn);
            Hn[((d >> 5) * 64 + ((d >> 3) & 3) * 16 + bl) * 8 + (d & 7)] = (_Float16)h;
        }
    }
    __syncthreads();

    const half8* Hn8 = (const half8*)Hn + lane;
    const half8* FW = (const half8*)fcWpk + lane;
#pragma unroll
    for (int oti = 0; oti < 4; ++oti) {
        int ot = w * 4 + oti;
        f32x4 acc = {0.f, 0.f, 0.f, 0.f};
        for (int kc = 0; kc < 32; ++kc) {
            half8 a  = FW[((size_t)ot * 32 + kc) * 64];
            half8 bf = Hn8[kc * 64];
            acc = __builtin_amdgcn_mfma_f32_16x16x32_f16(a, bf, acc, 0, 0, 0);
        }
#pragma unroll
        for (int r = 0; r < 4; ++r) {
            int o = ot * 16 + q * 4 + r;
            outl[bl][o] = acc[r] + fcb[o];
        }
    }
    __syncthreads();

#pragma unroll
    for (int i = 0; i < 16; ++i) {
        int b = bq4 * 16 + i;
        out[((size_t)b * TT_ + t) * OO + tid] = outl[i][tid];
    }
}

extern "C" void kernel_launch(void* const* d_in, const int* in_sizes, int n_in,
                              void* d_out, int out_size, void* d_ws, size_t ws_size,
                              hipStream_t stream) {
    const float* x    = (const float*)d_in[0];
    const float* eWih = (const float*)d_in[1];
    const float* eWhh = (const float*)d_in[2];
    const float* ebih = (const float*)d_in[3];
    const float* ebhh = (const float*)d_in[4];
    const float* dWih = (const float*)d_in[5];
    const float* dWhh = (const float*)d_in[6];
    const float* dbih = (const float*)d_in[7];
    const float* dbhh = (const float*)d_in[8];
    const float* fcW  = (const float*)d_in[9];
    const float* fcb  = (const float*)d_in[10];

    // ws layout (f32 words): hT 65536 | cT 65536 | hdecg 262144 | biasc 4096 |
    // flags 256 | fp16: Hf0 65536 | Hf1 65536 | Apk 5242880 | Xpk 8388608 |
    // Adecpk 1048576 | fcWpk 262144
    float* ws    = (float*)d_ws;
    float* hT    = ws;
    float* cT    = ws + 65536;
    float* hdecg = ws + 131072;
    float* biasc = ws + 393216;
    int*   flags = (int*)(ws + 397312);
    _Float16* fp  = (_Float16*)(ws + 397568);
    _Float16* Hf0 = fp;
    _Float16* Hf1 = fp + 65536;
    _Float16* Apk = fp + 131072;
    _Float16* Xpk = Apk + 5242880;
    _Float16* Adecpk = Xpk + 8388608;
    _Float16* fcWpk  = Adecpk + 1048576;

    pack_a2<<<dim3(2560), dim3(256), 0, stream>>>(eWhh, eWih, Apk);
    pack_x<<<dim3(4096), dim3(256), 0, stream>>>(x, Xpk);
    pack_bias<<<dim3(16), dim3(256), 0, stream>>>(ebih, ebhh, biasc);
    pack_adec<<<dim3(512), dim3(256), 0, stream>>>(dWih, Adecpk);
    pack_fcw<<<dim3(128), dim3(256), 0, stream>>>(fcW, fcWpk);
    hipMemsetAsync(flags, 0, 256 * sizeof(int), stream);
    hipMemsetAsync(Hf0, 0, 65536 * sizeof(_Float16), stream);

    enc_persist<<<dim3(256), dim3(256), 0, stream>>>(
        Apk, Xpk, Hf0, Hf1, biasc, cT, hT, flags);

    hdec_kernel<<<dim3(256), dim3(256), 0, stream>>>(hT, dWhh, dbih, dbhh, hdecg);
    dec_mfma<<<dim3(2048), dim3(256), 0, stream>>>(Adecpk, fcWpk, Xpk, hdecg, cT,
                                                   fcb, (float*)d_out);
}